// Round 8
// baseline (516.665 us; speedup 1.0000x reference)
//
#include <hip/hip_runtime.h>
#include <hip/hip_bf16.h>

// Problem constants
#define NSEQ 2048
#define NB   4
#define DIM  2048
#define HN   1024          // heads = DIM/2
#define FC   6144          // 3*DIM feat cols
#define MROWS 8192         // NSEQ*NB
#define CHUNKS 64
#define CLEN 32            // NSEQ/CHUNKS
#define NCH  4096          // NB*HN channels

typedef __bf16 bf16x8_t __attribute__((ext_vector_type(8)));
typedef float  f32x4_t  __attribute__((ext_vector_type(4)));

__device__ __forceinline__ float sigm(float x){ return 1.f/(1.f + __expf(-x)); }
__device__ __forceinline__ float bflo(unsigned p){ return __uint_as_float(p << 16); }
__device__ __forceinline__ float bfhi(unsigned p){ return __uint_as_float(p & 0xffff0000u); }
__device__ __forceinline__ unsigned short f2bf(float f){
  union { __hip_bfloat16 h; unsigned short u; } cv;
  cv.h = __float2bfloat16(f);
  return cv.u;
}

// ---------------------------------------------------------------- convert f32 -> bf16
__global__ __launch_bounds__(256) void cvt_bf16_4(const float4* __restrict__ in,
                                                  ushort4* __restrict__ out, int n4){
  int i = blockIdx.x * blockDim.x + threadIdx.x;
  int st = gridDim.x * blockDim.x;
  for (; i < n4; i += st){
    float4 v = in[i];
    ushort4 r;
    r.x = f2bf(v.x); r.y = f2bf(v.y); r.z = f2bf(v.z); r.w = f2bf(v.w);
    out[i] = r;
  }
}

// ---------------------------------------------------------------- bf16 NT GEMM + bias
// 256x128 block tile, BK=32, 4 waves (2Mx2N), wave-tile 128x64, 2 blocks/CU.
// QUAD-buffered LDS (4 x 12KB = 48KB), prefetch distance 2, ONE raw s_barrier per
// K-tile, COUNTED vmcnt(12) before it (never 0 in-loop, T4):
//   tile t: stage(t+2)->buf[(t+2)&3]; vmcnt(12) [ensures stage(t) landed; {t+1,t+2}
//   stay in flight]; s_barrier; ds_read 12 frags of buf[t&3]; 32 MFMA (counted lgkm
//   by compiler). Overwrite ledger: stage(t+2) hits buf[(t-2)&3]; its readers' MFMAs
//   forced lgkm-drain of those reads before barrier(t-1) -> >=2 barriers upstream. Tail:
//   vmcnt(6)/(0) when fewer stages outstanding. HBM latency spans 2 tiles (~2700cy).
// LDS layout r5/r7-verified conflict-free: 128B lines (2 rows x 32 el), granule
// glog=(row&1)*4+kg, phys = glog ^ (line&7); linear gl_lds dest + pre-swizzled source.
__device__ __forceinline__ void gl_lds16(const void* g, void* l){
  __builtin_amdgcn_global_load_lds((const __attribute__((address_space(1))) void*)g,
                                   (__attribute__((address_space(3))) void*)l, 16, 0, 0);
}

template <typename OutT>
__global__ __launch_bounds__(256, 2) void gemm256x128(const __hip_bfloat16* __restrict__ A,
                                                      const __hip_bfloat16* __restrict__ B,
                                                      const float* __restrict__ bias,
                                                      OutT* __restrict__ C,
                                                      int M, int N, int K, int nbx){
  // per buffer: A 256x32 (8192 el) + B 128x32 (4096 el) = 24 KB... elements: 12288; x4 = 96 KB? No:
  // 12288 el * 2B = 24KB per buffer; 4 buffers = 96KB > 48KB goal. Use 12KB buffers? No —
  // buffer must hold the full K-tile: 24KB. 4 x 24KB = 96KB -> 1 block... SO: use BK=32 with
  // A-half? Keep 4 x 24KB = 96KB and accept 1 block/CU? No: keep 2 blocks/CU by 4 bufs of
  // HALF size is wrong. Compromise: 3 buffers (72KB) won't give barrier distance. Resolution:
  // 4 buffers x 12KB via BK=16 doubles barrier rate. Chosen: 4 x 24KB = 96KB, 1 block/CU is
  // NOT taken; instead 2 blocks/CU with 48KB = 2 buffers + counted vmcnt needs the 2-barrier
  // trick. Final decision (see theory): 4 bufs x 12KB with BLOCK tile 128x128 (A 128x32=8KB,
  // B 128x32... ) -- simplest consistent config: block 128x128, 4 waves (2x2), wave 64x64,
  // buf = (128+128)x32 el = 16KB?? -> A 8KB + B 8KB = 16KB... 4x16KB = 64KB -> 2 blocks = 128KB.
  // FINAL: block 128x128, wave-tile 64x64 (4x4 frags), buf 16KB, 4 bufs = 64KB, 2 blocks/CU.
  __shared__ __align__(16) __hip_bfloat16 smem[4*8192];
  const int tid  = threadIdx.x;
  const int wave = tid >> 6, lane = tid & 63;

  // T1: bijective XCD swizzle (gridDim.x % 8 == 0 by launch)
  const int cpx = gridDim.x >> 3;
  const int wg  = (blockIdx.x & 7) * cpx + (blockIdx.x >> 3);
  const int bx = wg % nbx, by = wg / nbx;
  const int m0 = by * 128, n0 = bx * 128;

  const int wr = wave >> 1, wc = wave & 1;   // 2M x 2N waves, wave-tile 64x64
  const int r  = lane & 15, q = lane >> 4;   // fragment row / k-granule
  const int NT = K >> 5;                     // BK=32

  // swizzled ds_read offsets (elems within 4096-el A or B panel), conflict-free
  int aoff[4], boff[4];
  #pragma unroll
  for (int f = 0; f < 4; ++f){
    int R = wr*64 + f*16 + r;
    aoff[f] = (R>>1)*64 + (((((R&1)<<2) | q) ^ ((R>>1)&7)) << 3);
    int Rb = wc*64 + f*16 + r;
    boff[f] = (Rb>>1)*64 + (((((Rb&1)<<2) | q) ^ ((Rb>>1)&7)) << 3);
  }

  // stage one K-tile (A 128x32 + B 128x32 = 1024 granules, 4/thread); linear LDS dest,
  // pre-swizzled global source (same involution as the read offsets).
  auto stage = [&](int kt, int bo){
    #pragma unroll
    for (int i = 0; i < 2; ++i){
      int g = i*256 + tid;
      int line = g >> 3, glog = (g & 7) ^ (line & 7);
      int row = line*2 + (glog >> 2), kg = glog & 3;
      gl_lds16(A + (size_t)(m0 + row)*K + kt + kg*8, smem + bo + g*8);
      gl_lds16(B + (size_t)(n0 + row)*K + kt + kg*8, smem + bo + 4096 + g*8);
    }
  };

  f32x4_t acc[4][4] = {};

  stage(0, 0);            // 4 loads/thread each
  stage(32, 8192);
  for (int t = 0; t < NT; ++t){
    if (t + 2 < NT) stage((t+2)*32, ((t+2)&3)*8192);
    // counted wait: stages for tiles >t stay in flight (4 loads each per thread)
    if (t + 2 < NT)      asm volatile("s_waitcnt vmcnt(8)" ::: "memory");
    else if (t + 1 < NT) asm volatile("s_waitcnt vmcnt(4)" ::: "memory");
    else                 asm volatile("s_waitcnt vmcnt(0)" ::: "memory");
    __builtin_amdgcn_s_barrier();
    const __hip_bfloat16* Ab = smem + (t&3)*8192;
    const __hip_bfloat16* Bb = Ab + 4096;
    bf16x8_t af[4], bfr[4];
    #pragma unroll
    for (int fn = 0; fn < 4; ++fn)
      bfr[fn] = *reinterpret_cast<const bf16x8_t*>(Bb + boff[fn]);
    #pragma unroll
    for (int fm = 0; fm < 4; ++fm)
      af[fm] = *reinterpret_cast<const bf16x8_t*>(Ab + aoff[fm]);
    __builtin_amdgcn_s_setprio(1);
    #pragma unroll
    for (int fm = 0; fm < 4; ++fm)
      #pragma unroll
      for (int fn = 0; fn < 4; ++fn)
        acc[fm][fn] = __builtin_amdgcn_mfma_f32_16x16x32_bf16(af[fm], bfr[fn], acc[fm][fn], 0, 0, 0);
    __builtin_amdgcn_s_setprio(0);
    // no end barrier, no vmcnt(0): next iteration's counted wait + barrier handle it.
    // MFMAs consumed all 8 reads -> lgkm drained before next barrier (overwrite ledger).
  }

  // epilogue: C/D layout col = lane&15, row = (lane>>4)*4 + j  (m89-verified)
  #pragma unroll
  for (int fn = 0; fn < 4; ++fn){
    int col = n0 + wc*64 + fn*16 + r;
    float bv = bias[col];
    #pragma unroll
    for (int fm = 0; fm < 4; ++fm){
      int row0 = m0 + wr*64 + fm*16 + q*4;
      #pragma unroll
      for (int j = 0; j < 4; ++j){
        float v = acc[fm][fn][j] + bv;
        if constexpr (__is_same(OutT, float))
          C[(size_t)(row0 + j)*N + col] = v;
        else
          C[(size_t)(row0 + j)*N + col] = __float2bfloat16(v);
      }
    }
  }
}

// ---------------------------------------------------------------- scan helpers
// feat viewed as uint pairs: row(n,b) = n*NB+b; uint offset = (n*NB+b)*3072 + h
//   + 0    -> inp pair (cols 2h, 2h+1)
//   + 1024 -> og  pair
//   + 2048 -> fg  pair
struct SV { float l0, l1, u00, u01, u10, u11; };
__device__ __forceinline__ SV stepp(unsigned pi, unsigned pf){
  SV s;
  s.l0 = sigm(bflo(pf)); s.l1 = sigm(bfhi(pf));
  float i0 = bflo(pi), i1 = bfhi(pi);
  i0 *= sigm(i0); i1 *= sigm(i1);            // silu
  float a0 = 1.f - s.l0, a1 = 1.f - s.l1;
  s.u00 = a0*i0; s.u01 = a0*i1; s.u10 = a1*i0; s.u11 = a1*i1;
  return s;
}

// S1: per-(channel, chunk) aggregates; one-pass feat read with register stash.
__global__ __launch_bounds__(256) void scan_agg(const unsigned* __restrict__ feat,
    float* __restrict__ aggP, float4* __restrict__ aggHF, float4* __restrict__ aggHR){
  int ch = blockIdx.x*256 + threadIdx.x;   // 0..4095  (b*HN + h)
  int c  = blockIdx.y;
  int b = ch >> 10, h = ch & 1023;
  int base = b*3072 + h;
  int n0 = c*CLEN;
  unsigned spi[CLEN], spf[CLEN];
  float P0 = 1.f, P1 = 1.f;
  float f00=0,f01=0,f10=0,f11=0;
  #pragma unroll
  for (int t = 0; t < CLEN; ++t){
    int rowu = (n0+t)*12288 + base;
    spi[t] = feat[rowu];
    spf[t] = feat[rowu + 2048];
    SV s = stepp(spi[t], spf[t]);
    f00 = s.l0*f00 + s.u00; f01 = s.l0*f01 + s.u01;
    f10 = s.l1*f10 + s.u10; f11 = s.l1*f11 + s.u11;
    P0 *= s.l0; P1 *= s.l1;
  }
  float r00=0,r01=0,r10=0,r11=0;
  #pragma unroll
  for (int t = CLEN-1; t >= 0; --t){
    SV s = stepp(spi[t], spf[t]);
    r00 = s.l0*r00 + s.u00; r01 = s.l0*r01 + s.u01;
    r10 = s.l1*r10 + s.u10; r11 = s.l1*r11 + s.u11;
  }
  aggP[c*8192 + ch*2]     = P0;
  aggP[c*8192 + ch*2 + 1] = P1;
  aggHF[c*4096 + ch] = make_float4(f00,f01,f10,f11);
  aggHR[c*4096 + ch] = make_float4(r00,r01,r10,r11);
}

// S2: serial scan over chunk aggregates -> per-chunk carry-in states.
__global__ __launch_bounds__(256) void scan_carry(const float* __restrict__ aggP,
    const float* __restrict__ aggHF, const float* __restrict__ aggHR,
    float* __restrict__ cF, float* __restrict__ cR){
  int t  = blockIdx.x*256 + threadIdx.x;   // 0..16383
  int pd = t >> 1;                         // ch*2 + d
  float s = 0.f;
  for (int c = 0; c < CHUNKS; ++c){
    cF[c*16384 + t] = s;
    s = aggP[c*8192 + pd]*s + aggHF[c*16384 + t];
  }
  s = 0.f;
  for (int c = CHUNKS-1; c >= 0; --c){
    cR[c*16384 + t] = s;
    s = aggP[c*8192 + pd]*s + aggHR[c*16384 + t];
  }
}

// S3 fused: fwd pass reads feat ONCE into a register stash (static-indexed) and
// accumulates gated outputs; rev pass reuses the stash (no re-read); single write.
__global__ __launch_bounds__(256, 1) void scan_fr(const unsigned* __restrict__ feat,
    const float4* __restrict__ cF, const float4* __restrict__ cR,
    float2* __restrict__ o){
  int ch = blockIdx.x*256 + threadIdx.x;
  int c  = blockIdx.y;
  int b = ch >> 10, h = ch & 1023;
  int base = b*3072 + h;
  unsigned spi[CLEN], spf[CLEN], spo[CLEN];
  float2 accv[CLEN];
  {
    float4 hv = cF[c*4096 + ch];
    float h00=hv.x, h01=hv.y, h10=hv.z, h11=hv.w;
    #pragma unroll
    for (int t = 0; t < CLEN; ++t){
      int rowu = (c*CLEN + t)*12288 + base;
      spi[t] = feat[rowu];
      spo[t] = feat[rowu + 1024];
      spf[t] = feat[rowu + 2048];
      SV s = stepp(spi[t], spf[t]);
      h00 = s.l0*h00 + s.u00; h01 = s.l0*h01 + s.u01;
      h10 = s.l1*h10 + s.u10; h11 = s.l1*h11 + s.u11;
      float g0 = sigm(bflo(spo[t])), g1 = sigm(bfhi(spo[t]));
      accv[t] = make_float2(g0*h00 + g1*h10, g0*h01 + g1*h11);
    }
  }
  {
    float4 hv = cR[c*4096 + ch];
    float h00=hv.x, h01=hv.y, h10=hv.z, h11=hv.w;
    #pragma unroll
    for (int t = CLEN-1; t >= 0; --t){
      SV s = stepp(spi[t], spf[t]);
      h00 = s.l0*h00 + s.u00; h01 = s.l0*h01 + s.u01;
      h10 = s.l1*h10 + s.u10; h11 = s.l1*h11 + s.u11;
      float g0 = sigm(bflo(spo[t])), g1 = sigm(bfhi(spo[t]));
      accv[t].x += g0*h00 + g1*h10;
      accv[t].y += g0*h01 + g1*h11;
    }
  }
  #pragma unroll
  for (int t = 0; t < CLEN; ++t)
    o[((c*CLEN + t)*NB + b)*1024 + h] = accv[t];
}

// ---------------------------------------------------------------- LayerNorm over D, bf16 out
__global__ __launch_bounds__(256) void layernorm_k(const float* __restrict__ o,
    const float* __restrict__ gamma, const float* __restrict__ beta,
    __hip_bfloat16* __restrict__ out){
  int row = blockIdx.x, t = threadIdx.x;
  const float4* x = (const float4*)(o + (size_t)row*DIM);
  float4 a = x[t], b = x[t + 256];
  float s  = (a.x + a.y) + (a.z + a.w) + (b.x + b.y) + (b.z + b.w);
  float ss = (a.x*a.x + a.y*a.y) + (a.z*a.z + a.w*a.w)
           + (b.x*b.x + b.y*b.y) + (b.z*b.z + b.w*b.w);
  #pragma unroll
  for (int off = 32; off > 0; off >>= 1){
    s  += __shfl_down(s, off);
    ss += __shfl_down(ss, off);
  }
  __shared__ float red[8];
  int wv = t >> 6, ln = t & 63;
  if (ln == 0){ red[wv] = s; red[4 + wv] = ss; }
  __syncthreads();
  float S  = (red[0] + red[1]) + (red[2] + red[3]);
  float SS = (red[4] + red[5]) + (red[6] + red[7]);
  float mu = S * (1.f/DIM);
  float rs = rsqrtf(SS * (1.f/DIM) - mu*mu + 1e-5f);
  const float4* gp = (const float4*)gamma;
  const float4* bp = (const float4*)beta;
  float4 g0 = gp[t], g1 = gp[t + 256], be0 = bp[t], be1 = bp[t + 256];
  ushort4* op = (ushort4*)(out + (size_t)row*DIM);
  ushort4 r0, r1;
  r0.x = f2bf((a.x - mu)*rs*g0.x + be0.x);
  r0.y = f2bf((a.y - mu)*rs*g0.y + be0.y);
  r0.z = f2bf((a.z - mu)*rs*g0.z + be0.z);
  r0.w = f2bf((a.w - mu)*rs*g0.w + be0.w);
  r1.x = f2bf((b.x - mu)*rs*g1.x + be1.x);
  r1.y = f2bf((b.y - mu)*rs*g1.y + be1.y);
  r1.z = f2bf((b.z - mu)*rs*g1.z + be1.z);
  r1.w = f2bf((b.w - mu)*rs*g1.w + be1.w);
  op[t] = r0; op[t + 256] = r1;
}

// ---------------------------------------------------------------- launch
extern "C" void kernel_launch(void* const* d_in, const int* in_sizes, int n_in,
                              void* d_out, int out_size, void* d_ws, size_t ws_size,
                              hipStream_t stream){
  (void)in_sizes; (void)n_in; (void)out_size;
  const float* x     = (const float*)d_in[0];   // (N,B,D)
  const float* W_in  = (const float*)d_in[1];   // (3D,D)
  const float* b_in  = (const float*)d_in[2];   // (3D)
  const float* gamma = (const float*)d_in[3];   // (D)
  const float* beta  = (const float*)d_in[4];   // (D)
  const float* W_out = (const float*)d_in[5];   // (D,D)
  const float* b_out = (const float*)d_in[6];   // (D)
  float* out = (float*)d_out;                   // (N,B,D) fp32

  // ---- workspace layout with aliasing (total 186 MiB) ----
  char* p = (char*)d_ws;
  auto carve = [&](size_t bytes) -> char* {
    char* r = p; p += (bytes + 255) & ~(size_t)255; return r;
  };
  __hip_bfloat16* feat = (__hip_bfloat16*)carve((size_t)MROWS*FC*2);      // 96 MiB
  char* U              = carve((size_t)MROWS*DIM*4);                      // 64 MiB
  __hip_bfloat16* Wob  = (__hip_bfloat16*)carve((size_t)DIM*DIM*2);       //  8 MiB
  float* aggP  = (float*)carve((size_t)CHUNKS*8192*4);                    //  2 MiB
  float* aggHF = (float*)carve((size_t)CHUNKS*16384*4);                   //  4 MiB
  float* aggHR = (float*)carve((size_t)CHUNKS*16384*4);                   //  4 MiB
  float* cF    = (float*)carve((size_t)CHUNKS*16384*4);                   //  4 MiB
  float* cR    = (float*)carve((size_t)CHUNKS*16384*4);                   //  4 MiB
  if ((size_t)(p - (char*)d_ws) > ws_size) return;  // insufficient scratch

  __hip_bfloat16* xb  = (__hip_bfloat16*)U;                               // 32 MiB (phase 1)
  __hip_bfloat16* Wib = (__hip_bfloat16*)(U + (size_t)MROWS*DIM*2);       // 24 MiB (phase 1)
  float* o            = (float*)U;                                        // 64 MiB (phase 2+)
  __hip_bfloat16* oln = (__hip_bfloat16*)feat;                            // 32 MiB (phase 3)

  // 1) convert inputs to bf16
  cvt_bf16_4<<<2048, 256, 0, stream>>>((const float4*)x,     (ushort4*)xb,  MROWS*DIM/4);
  cvt_bf16_4<<<2048, 256, 0, stream>>>((const float4*)W_in,  (ushort4*)Wib, FC*DIM/4);
  cvt_bf16_4<<<1024, 256, 0, stream>>>((const float4*)W_out, (ushort4*)Wob, DIM*DIM/4);

  // 2) feat = x @ W_in^T + b_in   (8192 x 6144, K=2048), bf16 out; grid 3072 (%8==0)
  gemm256x128<__hip_bfloat16><<<3072, 256, 0, stream>>>(xb, Wib, b_in, feat, MROWS, FC, 2048, FC/128);

  // 3) bidirectional chunked linear scan + gated output projection to o (fp32)
  scan_agg  <<<dim3(NCH/256, CHUNKS), 256, 0, stream>>>((const unsigned*)feat, aggP, (float4*)aggHF, (float4*)aggHR);
  scan_carry<<<64, 256, 0, stream>>>(aggP, aggHF, aggHR, cF, cR);
  scan_fr   <<<dim3(NCH/256, CHUNKS), 256, 0, stream>>>((const unsigned*)feat, (const float4*)cF, (const float4*)cR, (float2*)o);

  // 4) LayerNorm -> bf16 (oln aliases feat, which is now dead)
  layernorm_k<<<MROWS, 256, 0, stream>>>(o, gamma, beta, oln);

  // 5) out = o_ln @ W_out^T + b_out  (8192 x 2048, K=2048), fp32 out; grid 1024 (%8==0)
  gemm256x128<float><<<1024, 256, 0, stream>>>(oln, Wob, b_out, out, MROWS, DIM, 2048, DIM/128);
}

// Round 9
// 459.478 us; speedup vs baseline: 1.1245x; 1.1245x over previous
//
#include <hip/hip_runtime.h>
#include <hip/hip_bf16.h>

// Problem constants
#define NSEQ 2048
#define NB   4
#define DIM  2048
#define HN   1024          // heads = DIM/2
#define FC   6144          // 3*DIM feat cols
#define MROWS 8192         // NSEQ*NB
#define CHUNKS 64
#define CLEN 32            // NSEQ/CHUNKS
#define NCH  4096          // NB*HN channels

typedef __bf16 bf16x8_t __attribute__((ext_vector_type(8)));
typedef float  f32x4_t  __attribute__((ext_vector_type(4)));

__device__ __forceinline__ float sigm(float x){ return 1.f/(1.f + __expf(-x)); }
__device__ __forceinline__ float bflo(unsigned p){ return __uint_as_float(p << 16); }
__device__ __forceinline__ float bfhi(unsigned p){ return __uint_as_float(p & 0xffff0000u); }
__device__ __forceinline__ unsigned short f2bf(float f){
  union { __hip_bfloat16 h; unsigned short u; } cv;
  cv.h = __float2bfloat16(f);
  return cv.u;
}

// ---------------------------------------------------------------- convert f32 -> bf16
__global__ __launch_bounds__(256) void cvt_bf16_4(const float4* __restrict__ in,
                                                  ushort4* __restrict__ out, int n4){
  int i = blockIdx.x * blockDim.x + threadIdx.x;
  int st = gridDim.x * blockDim.x;
  for (; i < n4; i += st){
    float4 v = in[i];
    ushort4 r;
    r.x = f2bf(v.x); r.y = f2bf(v.y); r.z = f2bf(v.z); r.w = f2bf(v.w);
    out[i] = r;
  }
}

// ---------------------------------------------------------------- bf16 NT GEMM + bias
// r7 GEOMETRY x r8 SCHEDULE.
// 256x128 block tile, BK=32, 4 waves (2Mx2N), wave-tile 128x64 (8x4 frags, 16x16x32).
// TRIPLE-buffered LDS (3 x 24KB = 72KB -> 2 blocks/CU), prefetch distance 2, ONE raw
// s_barrier per K-tile, COUNTED vmcnt(6) before it (never 0 until the last tile, T4).
// Iter t body: vmcnt(6) [stage(t) landed; stage(t+1)'s 6 loads stay in flight];
//   s_barrier; sched_barrier(0); stage(t+2) -> buf[(t+2)%3]; ds_read 12 frags of
//   buf[t%3]; 32 MFMA (compiler inserts counted lgkm).
// Race ledger: stage(t+2) targets buf[(t-1)%3]; every wave's reads(t-1) were consumed
// by its MFMA(t-1) (lgkm drain) before it reached barrier(t), and stage(t+2) is issued
// after barrier(t) -> cross-wave safe with 3 buffers. HBM latency spans 2 tiles.
// LDS layout r5/r7-verified conflict-free: 128B lines (2 rows x 32 el), granule
// glog=(row&1)*4+kg, phys = glog ^ (line&7); linear gl_lds dest + pre-swizzled source.
__device__ __forceinline__ void gl_lds16(const void* g, void* l){
  __builtin_amdgcn_global_load_lds((const __attribute__((address_space(1))) void*)g,
                                   (__attribute__((address_space(3))) void*)l, 16, 0, 0);
}

template <typename OutT>
__global__ __launch_bounds__(256, 2) void gemm256x128(const __hip_bfloat16* __restrict__ A,
                                                      const __hip_bfloat16* __restrict__ B,
                                                      const float* __restrict__ bias,
                                                      OutT* __restrict__ C,
                                                      int M, int N, int K, int nbx){
  // per buffer: A 256x32 (8192 el) + B 128x32 (4096 el) = 12288 el = 24KB; x3 = 72KB
  __shared__ __align__(16) __hip_bfloat16 smem[3*12288];
  const int tid  = threadIdx.x;
  const int wave = tid >> 6, lane = tid & 63;

  // T1: bijective XCD swizzle (gridDim.x % 8 == 0 by launch)
  const int cpx = gridDim.x >> 3;
  const int wg  = (blockIdx.x & 7) * cpx + (blockIdx.x >> 3);
  const int bx = wg % nbx, by = wg / nbx;
  const int m0 = by * 256, n0 = bx * 128;

  const int wr = wave >> 1, wc = wave & 1;   // 2M x 2N waves, wave-tile 128x64
  const int r  = lane & 15, q = lane >> 4;   // fragment row / k-granule
  const int NT = K >> 5;                     // BK=32

  // swizzled ds_read offsets (elems), r7-verified conflict-free
  int aoff[8], boff[4];
  #pragma unroll
  for (int f = 0; f < 8; ++f){
    int R = wr*128 + f*16 + r;
    aoff[f] = (R>>1)*64 + (((((R&1)<<2) | q) ^ ((R>>1)&7)) << 3);
  }
  #pragma unroll
  for (int n = 0; n < 4; ++n){
    int R = wc*64 + n*16 + r;
    boff[n] = (R>>1)*64 + (((((R&1)<<2) | q) ^ ((R>>1)&7)) << 3);
  }

  // stage one K-tile: A 1024 granules (4/thread) + B 512 (2/thread) = 6 gl_lds/thread;
  // linear LDS dest, pre-swizzled global source (same involution as the read offsets).
  auto stage = [&](int kt, int bo){
    #pragma unroll
    for (int i = 0; i < 4; ++i){
      int g = i*256 + tid;
      int line = g >> 3, glog = (g & 7) ^ (line & 7);
      int row = line*2 + (glog >> 2), kg = glog & 3;
      gl_lds16(A + (size_t)(m0 + row)*K + kt + kg*8, smem + bo + g*8);
    }
    #pragma unroll
    for (int i = 0; i < 2; ++i){
      int g = i*256 + tid;
      int line = g >> 3, glog = (g & 7) ^ (line & 7);
      int row = line*2 + (glog >> 2), kg = glog & 3;
      gl_lds16(B + (size_t)(n0 + row)*K + kt + kg*8, smem + bo + 8192 + g*8);
    }
  };

  f32x4_t acc[8][4] = {};

  stage(0, 0);
  stage(32, 12288);
  for (int t = 0; t < NT; ++t){
    if (t + 1 < NT) asm volatile("s_waitcnt vmcnt(6)" ::: "memory");
    else            asm volatile("s_waitcnt vmcnt(0)" ::: "memory");
    __builtin_amdgcn_s_barrier();
    __builtin_amdgcn_sched_barrier(0);        // pin ds_reads below the barrier
    if (t + 2 < NT) stage((t+2)*32, ((t+2)%3)*12288);
    const __hip_bfloat16* Ab = smem + (t%3)*12288;
    const __hip_bfloat16* Bb = Ab + 8192;
    bf16x8_t af[8], bfr[4];
    #pragma unroll
    for (int fn = 0; fn < 4; ++fn)
      bfr[fn] = *reinterpret_cast<const bf16x8_t*>(Bb + boff[fn]);
    #pragma unroll
    for (int fm = 0; fm < 8; ++fm)
      af[fm] = *reinterpret_cast<const bf16x8_t*>(Ab + aoff[fm]);
    __builtin_amdgcn_s_setprio(1);
    #pragma unroll
    for (int fm = 0; fm < 8; ++fm)
      #pragma unroll
      for (int fn = 0; fn < 4; ++fn)
        acc[fm][fn] = __builtin_amdgcn_mfma_f32_16x16x32_bf16(af[fm], bfr[fn], acc[fm][fn], 0, 0, 0);
    __builtin_amdgcn_s_setprio(0);
    // no trailing barrier/drain: next iteration's vmcnt+barrier carry the ledger
  }

  // epilogue: C/D layout col = lane&15, row = (lane>>4)*4 + j  (m89-verified)
  #pragma unroll
  for (int fn = 0; fn < 4; ++fn){
    int col = n0 + wc*64 + fn*16 + r;
    float bv = bias[col];
    #pragma unroll
    for (int fm = 0; fm < 8; ++fm){
      int row0 = m0 + wr*128 + fm*16 + q*4;
      #pragma unroll
      for (int j = 0; j < 4; ++j){
        float v = acc[fm][fn][j] + bv;
        if constexpr (__is_same(OutT, float))
          C[(size_t)(row0 + j)*N + col] = v;
        else
          C[(size_t)(row0 + j)*N + col] = __float2bfloat16(v);
      }
    }
  }
}

// ---------------------------------------------------------------- scan helpers
// feat viewed as uint pairs: row(n,b) = n*NB+b; uint offset = (n*NB+b)*3072 + h
//   + 0    -> inp pair (cols 2h, 2h+1)
//   + 1024 -> og  pair
//   + 2048 -> fg  pair
struct SV { float l0, l1, u00, u01, u10, u11; };
__device__ __forceinline__ SV stepp(unsigned pi, unsigned pf){
  SV s;
  s.l0 = sigm(bflo(pf)); s.l1 = sigm(bfhi(pf));
  float i0 = bflo(pi), i1 = bfhi(pi);
  i0 *= sigm(i0); i1 *= sigm(i1);            // silu
  float a0 = 1.f - s.l0, a1 = 1.f - s.l1;
  s.u00 = a0*i0; s.u01 = a0*i1; s.u10 = a1*i0; s.u11 = a1*i1;
  return s;
}

// S1: per-(channel, chunk) aggregates; one-pass feat read with register stash.
__global__ __launch_bounds__(256) void scan_agg(const unsigned* __restrict__ feat,
    float* __restrict__ aggP, float4* __restrict__ aggHF, float4* __restrict__ aggHR){
  int ch = blockIdx.x*256 + threadIdx.x;   // 0..4095  (b*HN + h)
  int c  = blockIdx.y;
  int b = ch >> 10, h = ch & 1023;
  int base = b*3072 + h;
  int n0 = c*CLEN;
  unsigned spi[CLEN], spf[CLEN];
  float P0 = 1.f, P1 = 1.f;
  float f00=0,f01=0,f10=0,f11=0;
  #pragma unroll
  for (int t = 0; t < CLEN; ++t){
    int rowu = (n0+t)*12288 + base;
    spi[t] = feat[rowu];
    spf[t] = feat[rowu + 2048];
    SV s = stepp(spi[t], spf[t]);
    f00 = s.l0*f00 + s.u00; f01 = s.l0*f01 + s.u01;
    f10 = s.l1*f10 + s.u10; f11 = s.l1*f11 + s.u11;
    P0 *= s.l0; P1 *= s.l1;
  }
  float r00=0,r01=0,r10=0,r11=0;
  #pragma unroll
  for (int t = CLEN-1; t >= 0; --t){
    SV s = stepp(spi[t], spf[t]);
    r00 = s.l0*r00 + s.u00; r01 = s.l0*r01 + s.u01;
    r10 = s.l1*r10 + s.u10; r11 = s.l1*r11 + s.u11;
  }
  aggP[c*8192 + ch*2]     = P0;
  aggP[c*8192 + ch*2 + 1] = P1;
  aggHF[c*4096 + ch] = make_float4(f00,f01,f10,f11);
  aggHR[c*4096 + ch] = make_float4(r00,r01,r10,r11);
}

// S2: serial scan over chunk aggregates -> per-chunk carry-in states.
__global__ __launch_bounds__(256) void scan_carry(const float* __restrict__ aggP,
    const float* __restrict__ aggHF, const float* __restrict__ aggHR,
    float* __restrict__ cF, float* __restrict__ cR){
  int t  = blockIdx.x*256 + threadIdx.x;   // 0..16383
  int pd = t >> 1;                         // ch*2 + d
  float s = 0.f;
  for (int c = 0; c < CHUNKS; ++c){
    cF[c*16384 + t] = s;
    s = aggP[c*8192 + pd]*s + aggHF[c*16384 + t];
  }
  s = 0.f;
  for (int c = CHUNKS-1; c >= 0; --c){
    cR[c*16384 + t] = s;
    s = aggP[c*8192 + pd]*s + aggHR[c*16384 + t];
  }
}

// S3 fused: fwd pass reads feat ONCE into a register stash (static-indexed) and
// accumulates gated outputs; rev pass reuses the stash (no re-read); single write.
__global__ __launch_bounds__(256, 1) void scan_fr(const unsigned* __restrict__ feat,
    const float4* __restrict__ cF, const float4* __restrict__ cR,
    float2* __restrict__ o){
  int ch = blockIdx.x*256 + threadIdx.x;
  int c  = blockIdx.y;
  int b = ch >> 10, h = ch & 1023;
  int base = b*3072 + h;
  unsigned spi[CLEN], spf[CLEN], spo[CLEN];
  float2 accv[CLEN];
  {
    float4 hv = cF[c*4096 + ch];
    float h00=hv.x, h01=hv.y, h10=hv.z, h11=hv.w;
    #pragma unroll
    for (int t = 0; t < CLEN; ++t){
      int rowu = (c*CLEN + t)*12288 + base;
      spi[t] = feat[rowu];
      spo[t] = feat[rowu + 1024];
      spf[t] = feat[rowu + 2048];
      SV s = stepp(spi[t], spf[t]);
      h00 = s.l0*h00 + s.u00; h01 = s.l0*h01 + s.u01;
      h10 = s.l1*h10 + s.u10; h11 = s.l1*h11 + s.u11;
      float g0 = sigm(bflo(spo[t])), g1 = sigm(bfhi(spo[t]));
      accv[t] = make_float2(g0*h00 + g1*h10, g0*h01 + g1*h11);
    }
  }
  {
    float4 hv = cR[c*4096 + ch];
    float h00=hv.x, h01=hv.y, h10=hv.z, h11=hv.w;
    #pragma unroll
    for (int t = CLEN-1; t >= 0; --t){
      SV s = stepp(spi[t], spf[t]);
      h00 = s.l0*h00 + s.u00; h01 = s.l0*h01 + s.u01;
      h10 = s.l1*h10 + s.u10; h11 = s.l1*h11 + s.u11;
      float g0 = sigm(bflo(spo[t])), g1 = sigm(bfhi(spo[t]));
      accv[t].x += g0*h00 + g1*h10;
      accv[t].y += g0*h01 + g1*h11;
    }
  }
  #pragma unroll
  for (int t = 0; t < CLEN; ++t)
    o[((c*CLEN + t)*NB + b)*1024 + h] = accv[t];
}

// ---------------------------------------------------------------- LayerNorm over D, bf16 out
__global__ __launch_bounds__(256) void layernorm_k(const float* __restrict__ o,
    const float* __restrict__ gamma, const float* __restrict__ beta,
    __hip_bfloat16* __restrict__ out){
  int row = blockIdx.x, t = threadIdx.x;
  const float4* x = (const float4*)(o + (size_t)row*DIM);
  float4 a = x[t], b = x[t + 256];
  float s  = (a.x + a.y) + (a.z + a.w) + (b.x + b.y) + (b.z + b.w);
  float ss = (a.x*a.x + a.y*a.y) + (a.z*a.z + a.w*a.w)
           + (b.x*b.x + b.y*b.y) + (b.z*b.z + b.w*b.w);
  #pragma unroll
  for (int off = 32; off > 0; off >>= 1){
    s  += __shfl_down(s, off);
    ss += __shfl_down(ss, off);
  }
  __shared__ float red[8];
  int wv = t >> 6, ln = t & 63;
  if (ln == 0){ red[wv] = s; red[4 + wv] = ss; }
  __syncthreads();
  float S  = (red[0] + red[1]) + (red[2] + red[3]);
  float SS = (red[4] + red[5]) + (red[6] + red[7]);
  float mu = S * (1.f/DIM);
  float rs = rsqrtf(SS * (1.f/DIM) - mu*mu + 1e-5f);
  const float4* gp = (const float4*)gamma;
  const float4* bp = (const float4*)beta;
  float4 g0 = gp[t], g1 = gp[t + 256], be0 = bp[t], be1 = bp[t + 256];
  ushort4* op = (ushort4*)(out + (size_t)row*DIM);
  ushort4 r0, r1;
  r0.x = f2bf((a.x - mu)*rs*g0.x + be0.x);
  r0.y = f2bf((a.y - mu)*rs*g0.y + be0.y);
  r0.z = f2bf((a.z - mu)*rs*g0.z + be0.z);
  r0.w = f2bf((a.w - mu)*rs*g0.w + be0.w);
  r1.x = f2bf((b.x - mu)*rs*g1.x + be1.x);
  r1.y = f2bf((b.y - mu)*rs*g1.y + be1.y);
  r1.z = f2bf((b.z - mu)*rs*g1.z + be1.z);
  r1.w = f2bf((b.w - mu)*rs*g1.w + be1.w);
  op[t] = r0; op[t + 256] = r1;
}

// ---------------------------------------------------------------- launch
extern "C" void kernel_launch(void* const* d_in, const int* in_sizes, int n_in,
                              void* d_out, int out_size, void* d_ws, size_t ws_size,
                              hipStream_t stream){
  (void)in_sizes; (void)n_in; (void)out_size;
  const float* x     = (const float*)d_in[0];   // (N,B,D)
  const float* W_in  = (const float*)d_in[1];   // (3D,D)
  const float* b_in  = (const float*)d_in[2];   // (3D)
  const float* gamma = (const float*)d_in[3];   // (D)
  const float* beta  = (const float*)d_in[4];   // (D)
  const float* W_out = (const float*)d_in[5];   // (D,D)
  const float* b_out = (const float*)d_in[6];   // (D)
  float* out = (float*)d_out;                   // (N,B,D) fp32

  // ---- workspace layout with aliasing (total 186 MiB) ----
  char* p = (char*)d_ws;
  auto carve = [&](size_t bytes) -> char* {
    char* r = p; p += (bytes + 255) & ~(size_t)255; return r;
  };
  __hip_bfloat16* feat = (__hip_bfloat16*)carve((size_t)MROWS*FC*2);      // 96 MiB
  char* U              = carve((size_t)MROWS*DIM*4);                      // 64 MiB
  __hip_bfloat16* Wob  = (__hip_bfloat16*)carve((size_t)DIM*DIM*2);       //  8 MiB
  float* aggP  = (float*)carve((size_t)CHUNKS*8192*4);                    //  2 MiB
  float* aggHF = (float*)carve((size_t)CHUNKS*16384*4);                   //  4 MiB
  float* aggHR = (float*)carve((size_t)CHUNKS*16384*4);                   //  4 MiB
  float* cF    = (float*)carve((size_t)CHUNKS*16384*4);                   //  4 MiB
  float* cR    = (float*)carve((size_t)CHUNKS*16384*4);                   //  4 MiB
  if ((size_t)(p - (char*)d_ws) > ws_size) return;  // insufficient scratch

  __hip_bfloat16* xb  = (__hip_bfloat16*)U;                               // 32 MiB (phase 1)
  __hip_bfloat16* Wib = (__hip_bfloat16*)(U + (size_t)MROWS*DIM*2);       // 24 MiB (phase 1)
  float* o            = (float*)U;                                        // 64 MiB (phase 2+)
  __hip_bfloat16* oln = (__hip_bfloat16*)feat;                            // 32 MiB (phase 3)

  // 1) convert inputs to bf16
  cvt_bf16_4<<<2048, 256, 0, stream>>>((const float4*)x,     (ushort4*)xb,  MROWS*DIM/4);
  cvt_bf16_4<<<2048, 256, 0, stream>>>((const float4*)W_in,  (ushort4*)Wib, FC*DIM/4);
  cvt_bf16_4<<<1024, 256, 0, stream>>>((const float4*)W_out, (ushort4*)Wob, DIM*DIM/4);

  // 2) feat = x @ W_in^T + b_in   (8192 x 6144, K=2048), bf16 out; grid 1536 (%8==0)
  gemm256x128<__hip_bfloat16><<<1536, 256, 0, stream>>>(xb, Wib, b_in, feat, MROWS, FC, 2048, FC/128);

  // 3) bidirectional chunked linear scan + gated output projection to o (fp32)
  scan_agg  <<<dim3(NCH/256, CHUNKS), 256, 0, stream>>>((const unsigned*)feat, aggP, (float4*)aggHF, (float4*)aggHR);
  scan_carry<<<64, 256, 0, stream>>>(aggP, aggHF, aggHR, cF, cR);
  scan_fr   <<<dim3(NCH/256, CHUNKS), 256, 0, stream>>>((const unsigned*)feat, (const float4*)cF, (const float4*)cR, (float2*)o);

  // 4) LayerNorm -> bf16 (oln aliases feat, which is now dead)
  layernorm_k<<<MROWS, 256, 0, stream>>>(o, gamma, beta, oln);

  // 5) out = o_ln @ W_out^T + b_out  (8192 x 2048, K=2048), fp32 out; grid 512 (%8==0)
  gemm256x128<float><<<512, 256, 0, stream>>>(oln, Wob, b_out, out, MROWS, DIM, 2048, DIM/128);
}